// Round 9
// baseline (313.385 us; speedup 1.0000x reference)
//
#include <hip/hip_runtime.h>
#include <math.h>

#define NB 16384
#define LH 50
#define D  64

typedef _Float16 half2v __attribute__((ext_vector_type(2)));
typedef _Float16 half8  __attribute__((ext_vector_type(8)));
typedef float    f32x16 __attribute__((ext_vector_type(16)));
typedef unsigned int u32;

#define MFMA(a, b, c) __builtin_amdgcn_mfma_f32_32x32x16_f16((a), (b), (c), 0, 0, 0)

// ---- fragment facts (32x32x16, verified m74/m101 + R3..R8 pass) ----
// A[m][k]: m=lane&31, k=(lane>>5)*8+j   B[k][n]: n=lane&31, k=(lane>>5)*8+j
// C/D: col=lane&31, row=(reg&3)+8*(reg>>2)+4*(lane>>5)

__device__ __forceinline__ u32 pack2(float a, float b) {
    half2v h; h[0] = (_Float16)a; h[1] = (_Float16)b;
    return __builtin_bit_cast(u32, h);
}
__device__ __forceinline__ half8 mk8(u32 a, u32 b, u32 c, u32 d) {
    uint4 t = make_uint4(a, b, c, d);
    return __builtin_bit_cast(half8, t);
}
__device__ __forceinline__ half8 cvt8(const float* __restrict__ p) {
    float4 u = *(const float4*)p;
    float4 v = *(const float4*)(p + 4);
    return mk8(pack2(u.x, u.y), pack2(u.z, u.w), pack2(v.x, v.y), pack2(v.z, v.w));
}
__device__ __forceinline__ half8 cvt8v(float4 u, float4 v) {
    return mk8(pack2(u.x, u.y), pack2(u.z, u.w), pack2(v.x, v.y), pack2(v.z, v.w));
}

// relu + f16-pack + lane^32 exchange: one C tile -> two B-frags (k-halves)
__device__ __forceinline__ void xform_tile(const f32x16& t, int hv, half8& f0, half8& f1) {
    u32 p[8], rp[8];
    #pragma unroll
    for (int q = 0; q < 8; ++q) p[q] = pack2(fmaxf(t[2*q], 0.f), fmaxf(t[2*q+1], 0.f));
    #pragma unroll
    for (int q = 0; q < 8; ++q) rp[q] = (u32)__shfl_xor((int)p[q], 32, 64);
    f0 = hv ? mk8(rp[2], rp[3], p[2], p[3]) : mk8(p[0], p[1], rp[0], rp[1]);
    f1 = hv ? mk8(rp[6], rp[7], p[6], p[7]) : mk8(p[4], p[5], rp[4], rp[5]);
}

__device__ __forceinline__ f32x16 ldbias(const float* __restrict__ tbf, int hv, int mt) {
    const float4* p = (const float4*)tbf + hv*8 + mt*4;
    f32x16 r;
    #pragma unroll
    for (int q = 0; q < 4; ++q) {
        float4 v = p[q];
        r[4*q] = v.x; r[4*q+1] = v.y; r[4*q+2] = v.z; r[4*q+3] = v.w;
    }
    return r;
}

// weight B/A-frag from pre-formatted global table (L2-hot, coalesced b128)
__device__ __forceinline__ half8 wfrag(const _Float16* __restrict__ wsh, int base, int f, int lane) {
    return *(const half8*)(wsh + base + (size_t)(f*64 + lane)*8);
}

// ================= K1: weight/bias reorder into ws (unchanged, verified) ====
__global__ void uv_prep(const float* __restrict__ w1, const float* __restrict__ w2,
                        const float* __restrict__ wa1, const float* __restrict__ wa2,
                        const float* __restrict__ b1, const float* __restrict__ b2,
                        const float* __restrict__ ba1, const float* __restrict__ ba2,
                        const float* __restrict__ wa3,
                        _Float16* __restrict__ wsh, float* __restrict__ tbf) {
    const int idx = blockIdx.x * 256 + threadIdx.x;   // grid 96 -> idx < 24576
    const int j = idx & 7, lane = (idx >> 3) & 63;
    const int hv = lane >> 5, m31 = lane & 31;
    float v;
    if (idx < 8192)       { const int ks = (idx >> 9) & 7, mt = (idx >> 12) & 1;
        v = w1 [(ks*16 + hv*8 + j)*64 + mt*32 + m31]; }
    else if (idx < 12288) { const int ks = (idx >> 9) & 3, mt = (idx >> 11) & 1;
        v = w2 [(ks*16 + hv*8 + j)*64 + mt*32 + m31]; }
    else if (idx < 16384) { const int ks = (idx >> 9) & 3, mt = (idx >> 11) & 1;
        v = wa1[(ks*16 + hv*8 + j)*64 + mt*32 + m31]; }
    else if (idx < 20480) { const int ks = (idx >> 9) & 3, mt = (idx >> 11) & 1;
        v = wa1[(64 + ks*16 + hv*8 + j)*64 + mt*32 + m31]; }
    else                  { const int ks = (idx >> 9) & 3, mt = (idx >> 11) & 1;
        v = wa2[(ks*16 + hv*8 + j)*64 + mt*32 + m31]; }
    wsh[idx] = (_Float16)v;

    if (blockIdx.x == 0 && threadIdx.x < 64) {
        const int t = threadIdx.x;
        const int thv = t >> 5, r = t & 31, mt = r >> 4, i = r & 15;
        const int feat = mt*32 + (i & 3) + 8*(i >> 2) + 4*thv;
        tbf[t]       = b1[feat];
        tbf[64 + t]  = b2[feat];
        tbf[128 + t] = ba1[feat];
        tbf[192 + t] = ba2[feat];
        tbf[256 + t] = wa3[feat];
    }
}

// ---- per-node prefetched index bundle
struct Idx { int rid[8]; int ir0, ir1, nd; };

__device__ __forceinline__ Idx idxload(const int* __restrict__ huv,
                                       const int* __restrict__ hr,
                                       const int* __restrict__ nodes,
                                       int b, int n, int tg) {
    Idx x;
    #pragma unroll
    for (int j = 0; j < 8; ++j) {
        int t = j*8 + tg; if (t > LH-1) t = LH-1;
        x.rid[j] = huv[b*LH + t];
    }
    const int t1 = (32 + n < LH) ? 32 + n : LH - 1;
    x.ir0 = hr[b*LH + n];
    x.ir1 = hr[b*LH + t1];
    x.nd  = nodes[b];
    return x;
}

// coalesced v2e loads for one node: 16 float4 (8 rows x 2 chunks per lane)
__device__ __forceinline__ void dataload(const float* __restrict__ v2e,
                                         const Idx& x, int qq, float4* c) {
    #pragma unroll
    for (int j = 0; j < 8; ++j)
        c[j] = *(const float4*)(v2e + (size_t)x.rid[j]*D + qq*4);
    #pragma unroll
    for (int j = 0; j < 8; ++j)
        c[8 + j] = *(const float4*)(v2e + (size_t)x.rid[j]*D + 32 + qq*4);
}

// phase 1: stage v2e (R6 stride-65 pattern, 0 conflicts) + layer-1 item half.
// Consumes c[] completely so it can be refilled for the next node.
__device__ __forceinline__ void phase1(float4* __restrict__ stage, const float4* c,
        const float* __restrict__ tbf, const _Float16* __restrict__ wsh,
        int lane, int n, int hv, int qq, int tg,
        f32x16& a00, f32x16& a01, f32x16& a10, f32x16& a11) {
    #pragma unroll
    for (int j = 0; j < 8; ++j) stage[qq*65 + j*8 + tg] = c[j];
    {   // ks0 (bias tile as MFMA C)
        const f32x16 bc0 = ldbias(tbf, hv, 0), bc1 = ldbias(tbf, hv, 1);
        const int p0 = hv*2;
        half8 bf0 = cvt8v(stage[p0*65 + n],      stage[(p0+1)*65 + n]);
        half8 bf1 = cvt8v(stage[p0*65 + 32 + n], stage[(p0+1)*65 + 32 + n]);
        half8 w0 = wfrag(wsh, 0, 0, lane), w1f = wfrag(wsh, 0, 8, lane);
        a00 = MFMA(w0, bf0, bc0);  a01 = MFMA(w0, bf1, bc0);
        a10 = MFMA(w1f, bf0, bc1); a11 = MFMA(w1f, bf1, bc1);
    }
    {   // ks1
        const int p0 = 4 + hv*2;
        half8 bf0 = cvt8v(stage[p0*65 + n],      stage[(p0+1)*65 + n]);
        half8 bf1 = cvt8v(stage[p0*65 + 32 + n], stage[(p0+1)*65 + 32 + n]);
        half8 w0 = wfrag(wsh, 0, 1, lane), w1f = wfrag(wsh, 0, 9, lane);
        a00 = MFMA(w0, bf0, a00);  a01 = MFMA(w0, bf1, a01);
        a10 = MFMA(w1f, bf0, a10); a11 = MFMA(w1f, bf1, a11);
    }
    // chunk2 over the same planes (same-wave DS ordering covers WAR; R6-proven)
    #pragma unroll
    for (int j = 0; j < 8; ++j) stage[qq*65 + j*8 + tg] = c[8 + j];
    #pragma unroll
    for (int ks = 2; ks < 4; ++ks) {
        const int p0 = (ks - 2)*4 + hv*2;
        half8 bf0 = cvt8v(stage[p0*65 + n],      stage[(p0+1)*65 + n]);
        half8 bf1 = cvt8v(stage[p0*65 + 32 + n], stage[(p0+1)*65 + 32 + n]);
        half8 w0 = wfrag(wsh, 0, ks, lane), w1f = wfrag(wsh, 0, 8 + ks, lane);
        a00 = MFMA(w0, bf0, a00);  a01 = MFMA(w0, bf1, a01);
        a10 = MFMA(w1f, bf0, a10); a11 = MFMA(w1f, bf1, a11);
    }
}

// phase 2: rating half of layer 1 + layers 2..4 + softmax + epilogue + store
__device__ __forceinline__ void phase2(int b, const Idx& x,
        const float* __restrict__ tbf, const _Float16* __restrict__ wsh,
        const float* __restrict__ u2e, const float* __restrict__ r2e,
        float* __restrict__ out, int lane, int n, int hv,
        f32x16& a00, f32x16& a01, f32x16& a10, f32x16& a11) {
    // u-broadcast frags issued first (consumed at att1, ~1500cyc later)
    const float* urow = u2e + (size_t)x.nd * D + hv*8;
    half8 uf[4];
    #pragma unroll
    for (int ks = 0; ks < 4; ++ks) uf[ks] = cvt8(urow + ks*16);

    const float* xr0 = r2e + (size_t)x.ir0 * D + hv*8;
    const float* xr1 = r2e + (size_t)x.ir1 * D + hv*8;
    #pragma unroll
    for (int ks = 4; ks < 8; ++ks) {         // rating half (r2e: 5 rows, L1-hot)
        half8 bf0 = cvt8(xr0 + (ks - 4)*16);
        half8 bf1 = cvt8(xr1 + (ks - 4)*16);
        half8 w0 = wfrag(wsh, 0, ks, lane), w1f = wfrag(wsh, 0, 8 + ks, lane);
        a00 = MFMA(w0, bf0, a00);  a01 = MFMA(w0, bf1, a01);
        a10 = MFMA(w1f, bf0, a10); a11 = MFMA(w1f, bf1, a11);
    }
    half8 hf[2][4];
    xform_tile(a00, hv, hf[0][0], hf[0][1]); xform_tile(a01, hv, hf[1][0], hf[1][1]);
    xform_tile(a10, hv, hf[0][2], hf[0][3]); xform_tile(a11, hv, hf[1][2], hf[1][3]);

    // layer 2
    {
        const f32x16 bc0 = ldbias(tbf + 64, hv, 0), bc1 = ldbias(tbf + 64, hv, 1);
        half8 w0 = wfrag(wsh, 8192, 0, lane), w1f = wfrag(wsh, 8192, 4, lane);
        a00 = MFMA(w0, hf[0][0], bc0);  a01 = MFMA(w0, hf[1][0], bc0);
        a10 = MFMA(w1f, hf[0][0], bc1); a11 = MFMA(w1f, hf[1][0], bc1);
    }
    #pragma unroll
    for (int ks = 1; ks < 4; ++ks) {
        half8 w0 = wfrag(wsh, 8192, ks, lane), w1f = wfrag(wsh, 8192, 4 + ks, lane);
        a00 = MFMA(w0, hf[0][ks], a00);  a01 = MFMA(w0, hf[1][ks], a01);
        a10 = MFMA(w1f, hf[0][ks], a10); a11 = MFMA(w1f, hf[1][ks], a11);
    }
    half8 of[2][4];
    xform_tile(a00, hv, of[0][0], of[0][1]); xform_tile(a01, hv, of[1][0], of[1][1]);
    xform_tile(a10, hv, of[0][2], of[0][3]); xform_tile(a11, hv, of[1][2], of[1][3]);

    // att1 (+ u K-extension)
    {
        const f32x16 bc0 = ldbias(tbf + 128, hv, 0), bc1 = ldbias(tbf + 128, hv, 1);
        half8 w0 = wfrag(wsh, 12288, 0, lane), w1f = wfrag(wsh, 12288, 4, lane);
        a00 = MFMA(w0, of[0][0], bc0);  a01 = MFMA(w0, of[1][0], bc0);
        a10 = MFMA(w1f, of[0][0], bc1); a11 = MFMA(w1f, of[1][0], bc1);
    }
    #pragma unroll
    for (int ks = 1; ks < 4; ++ks) {
        half8 w0 = wfrag(wsh, 12288, ks, lane), w1f = wfrag(wsh, 12288, 4 + ks, lane);
        a00 = MFMA(w0, of[0][ks], a00);  a01 = MFMA(w0, of[1][ks], a01);
        a10 = MFMA(w1f, of[0][ks], a10); a11 = MFMA(w1f, of[1][ks], a11);
    }
    #pragma unroll
    for (int ks = 0; ks < 4; ++ks) {
        half8 w0 = wfrag(wsh, 16384, ks, lane), w1f = wfrag(wsh, 16384, 4 + ks, lane);
        a00 = MFMA(w0, uf[ks], a00);  a01 = MFMA(w0, uf[ks], a01);
        a10 = MFMA(w1f, uf[ks], a10); a11 = MFMA(w1f, uf[ks], a11);
    }
    half8 af[2][4];
    xform_tile(a00, hv, af[0][0], af[0][1]); xform_tile(a01, hv, af[1][0], af[1][1]);
    xform_tile(a10, hv, af[0][2], af[0][3]); xform_tile(a11, hv, af[1][2], af[1][3]);

    // att2 + logits
    float lg0 = 0.f, lg1 = 0.f;
    #pragma unroll
    for (int mt = 0; mt < 2; ++mt) {
        f32x16 c0, c1v;
        {
            const f32x16 bc = ldbias(tbf + 192, hv, mt);
            half8 w = wfrag(wsh, 20480, mt*4 + 0, lane);
            c0  = MFMA(w, af[0][0], bc);
            c1v = MFMA(w, af[1][0], bc);
        }
        #pragma unroll
        for (int ks = 1; ks < 4; ++ks) {
            half8 w = wfrag(wsh, 20480, mt*4 + ks, lane);
            c0  = MFMA(w, af[0][ks], c0);
            c1v = MFMA(w, af[1][ks], c1v);
        }
        #pragma unroll
        for (int q = 0; q < 4; ++q) {
            float4 w3 = ((const float4*)(tbf + 256))[hv*8 + mt*4 + q];
            lg0 += fmaxf(c0[4*q], 0.f)*w3.x + fmaxf(c0[4*q+1], 0.f)*w3.y
                 + fmaxf(c0[4*q+2], 0.f)*w3.z + fmaxf(c0[4*q+3], 0.f)*w3.w;
            lg1 += fmaxf(c1v[4*q], 0.f)*w3.x + fmaxf(c1v[4*q+1], 0.f)*w3.y
                 + fmaxf(c1v[4*q+2], 0.f)*w3.z + fmaxf(c1v[4*q+3], 0.f)*w3.w;
        }
    }
    lg0 += __shfl_xor(lg0, 32, 64);
    lg1 += __shfl_xor(lg1, 32, 64);
    if (32 + n >= LH) lg1 = -1e30f;

    float mx = fmaxf(lg0, lg1);
    #pragma unroll
    for (int off = 16; off >= 1; off >>= 1) mx = fmaxf(mx, __shfl_xor(mx, off, 64));
    const float e0 = __expf(lg0 - mx);
    const float e1 = __expf(lg1 - mx);
    float s = e0 + e1;
    #pragma unroll
    for (int off = 16; off >= 1; off >>= 1) s += __shfl_xor(s, off, 64);
    const float at0 = e0 / s, at1 = e1 / s;

    float cur[32];
    #pragma unroll
    for (int ks = 0; ks < 4; ++ks)
        #pragma unroll
        for (int j = 0; j < 8; ++j)
            cur[ks*8 + j] = at0 * (float)of[0][ks][j] + at1 * (float)of[1][ks][j];
    #pragma unroll
    for (int k = 0; k < 5; ++k) {
        const int d = 1 << k, mybit = (lane >> k) & 1, half = 16 >> k;
        #pragma unroll
        for (int j2 = 0; j2 < 16; ++j2) {
            if (j2 < half) {
                float sel  = mybit ? cur[2*j2]     : cur[2*j2 + 1];
                float got  = __shfl_xor(sel, d, 64);
                float keep = mybit ? cur[2*j2 + 1] : cur[2*j2];
                cur[j2] = keep + got;
            }
        }
    }
    const int feat = ((lane >> 3) & 3)*16 + hv*8 + (lane & 7);
    __builtin_nontemporal_store(cur[0], out + (size_t)b * D + feat);
}

// ================= K2: one wave per block, 4 nodes per wave, prefetched ====
__global__ __launch_bounds__(64) void uv_main(
    const int*   __restrict__ nodes,
    const int*   __restrict__ huv,
    const int*   __restrict__ hr,
    const float* __restrict__ v2e,
    const float* __restrict__ u2e,
    const float* __restrict__ r2e,
    const _Float16* __restrict__ wsh,
    const float* __restrict__ tbf,
    float*       __restrict__ out) {
    __shared__ float4 stage[520];            // 8.3 KB, reused across nodes (DS order)
    const int lane = threadIdx.x;
    const int n = lane & 31, hv = lane >> 5;
    const int tg = lane >> 3, qq = lane & 7;
    const int b0 = blockIdx.x * 4;

    Idx ix[4];
    float4 c[16];
    ix[0] = idxload(huv, hr, nodes, b0 + 0, n, tg);
    ix[1] = idxload(huv, hr, nodes, b0 + 1, n, tg);
    dataload(v2e, ix[0], qq, c);

    #pragma unroll
    for (int it = 0; it < 4; ++it) {
        f32x16 a00, a01, a10, a11;
        phase1(stage, c, tbf, wsh, lane, n, hv, qq, tg, a00, a01, a10, a11);
        if (it < 3) {                        // prefetch: overlap node it's layers 2..4
            if (it < 2) ix[it + 2] = idxload(huv, hr, nodes, b0 + it + 2, n, tg);
            dataload(v2e, ix[it + 1], qq, c);
        }
        __builtin_amdgcn_sched_barrier(0);   // pin prefetch issues above phase2
        phase2(b0 + it, ix[it], tbf, wsh, u2e, r2e, out, lane, n, hv,
               a00, a01, a10, a11);
    }
}

extern "C" void kernel_launch(void* const* d_in, const int* in_sizes, int n_in,
                              void* d_out, int out_size, void* d_ws, size_t ws_size,
                              hipStream_t stream) {
    const int*   nodes      = (const int*)  d_in[0];
    const int*   history_uv = (const int*)  d_in[1];
    const int*   history_r  = (const int*)  d_in[2];
    const float* v2e        = (const float*)d_in[3];
    const float* u2e        = (const float*)d_in[4];
    const float* r2e        = (const float*)d_in[5];
    const float* w1         = (const float*)d_in[6];
    const float* b1         = (const float*)d_in[7];
    const float* w2         = (const float*)d_in[8];
    const float* b2         = (const float*)d_in[9];
    const float* wa1        = (const float*)d_in[10];
    const float* ba1        = (const float*)d_in[11];
    const float* wa2        = (const float*)d_in[12];
    const float* ba2        = (const float*)d_in[13];
    const float* wa3        = (const float*)d_in[14];
    float* out = (float*)d_out;

    _Float16* wsh = (_Float16*)d_ws;
    float*    tbf = (float*)((char*)d_ws + 49152);

    uv_prep<<<96, 256, 0, stream>>>(w1, w2, wa1, wa2, b1, b2, ba1, ba2, wa3, wsh, tbf);
    uv_main<<<NB / 4, 64, 0, stream>>>(nodes, history_uv, history_r,
                                       v2e, u2e, r2e, wsh, tbf, out);
}